// Round 1
// baseline (105.266 us; speedup 1.0000x reference)
//
#include <hip/hip_runtime.h>
#include <math.h>

// Problem constants (from reference)
#define BB 8
#define NN 1024
#define CC 256
#define PARAM_DIM 16
#define EPS 1e-5f

// Block-wide sum over 256 threads (4 waves of 64).
__device__ __forceinline__ float block_sum(float x, float* red) {
    #pragma unroll
    for (int o = 32; o > 0; o >>= 1) x += __shfl_down(x, o, 64);
    __syncthreads();                       // protect red[] from previous use
    if ((threadIdx.x & 63) == 0) red[threadIdx.x >> 6] = x;
    __syncthreads();
    return red[0] + red[1] + red[2] + red[3];
}

// One block per batch (grid = 8, block = 256). Computes
//   ctx = param @ Wparam + bparam
//   ln  = layernorm(ctx, g, b)
//   v   = ln @ Wkv[:, C:2C]
//   y   = v @ Wout + bout
__global__ __launch_bounds__(CC) void compute_y_kernel(
    const float* __restrict__ param,    // (B, 16)
    const float* __restrict__ Wparam,   // (16, C)
    const float* __restrict__ bparam,   // (C,)
    const float* __restrict__ ctx_g,    // (C,)
    const float* __restrict__ ctx_b,    // (C,)
    const float* __restrict__ Wkv,      // (C, 2C)
    const float* __restrict__ Wout,     // (C, C)
    const float* __restrict__ bout,     // (C,)
    float* __restrict__ y)              // (B, C) out
{
    const int b = blockIdx.x;
    const int c = threadIdx.x;          // 0..255

    __shared__ float sm[CC];
    __shared__ float red[4];
    __shared__ float p[PARAM_DIM];

    if (c < PARAM_DIM) p[c] = param[b * PARAM_DIM + c];
    __syncthreads();

    // ctx[c] = bparam[c] + sum_j p[j] * Wparam[j][c]   (coalesced over c)
    float ctx = bparam[c];
    #pragma unroll
    for (int j = 0; j < PARAM_DIM; ++j)
        ctx = fmaf(p[j], Wparam[j * CC + c], ctx);

    // layernorm over the C=256 values held across the block
    float mean = block_sum(ctx, red) * (1.0f / CC);
    float d = ctx - mean;
    float var = block_sum(d * d, red) * (1.0f / CC);
    float ln = d * rsqrtf(var + EPS) * ctx_g[c] + ctx_b[c];

    __syncthreads();        // red[] done; also before writing sm
    sm[c] = ln;
    __syncthreads();

    // v[c] = sum_j ln[j] * Wkv[j][C + c]   (coalesced over c)
    float v = 0.0f;
    #pragma unroll 8
    for (int j = 0; j < CC; ++j)
        v = fmaf(sm[j], Wkv[j * (2 * CC) + CC + c], v);

    __syncthreads();        // everyone done reading sm
    sm[c] = v;
    __syncthreads();

    // y[c] = bout[c] + sum_j v[j] * Wout[j][c]
    float o = bout[c];
    #pragma unroll 8
    for (int j = 0; j < CC; ++j)
        o = fmaf(sm[j], Wout[j * CC + c], o);

    y[b * CC + c] = o;
}

// out[b,n,:] = img[b,n,:] + y[b,:]  — float4 vectorized.
// Grid exactly covers B*N*C/4 = 524288 float4 elements.
__global__ __launch_bounds__(256) void bcast_add_kernel(
    const float4* __restrict__ img4,
    const float4* __restrict__ y4,      // (B, 64) float4 rows
    float4* __restrict__ out4)
{
    const int i4 = blockIdx.x * blockDim.x + threadIdx.x;   // < 524288
    const int b  = i4 >> 16;            // N*C/4 = 65536 float4 per batch
    const int c4 = i4 & 63;             // C/4 = 64 float4 per row
    float4 a = img4[i4];
    float4 yy = y4[b * 64 + c4];
    a.x += yy.x; a.y += yy.y; a.z += yy.z; a.w += yy.w;
    out4[i4] = a;
}

extern "C" void kernel_launch(void* const* d_in, const int* in_sizes, int n_in,
                              void* d_out, int out_size, void* d_ws, size_t ws_size,
                              hipStream_t stream) {
    const float* img     = (const float*)d_in[0];   // (B, N, C)
    const float* param   = (const float*)d_in[1];   // (B, 16)
    // d_in[2] img_norm_g, d_in[3] img_norm_b, d_in[4] Wq  -> dead code
    const float* Wparam  = (const float*)d_in[5];   // (16, C)
    const float* bparam  = (const float*)d_in[6];   // (C,)
    const float* ctx_g   = (const float*)d_in[7];   // (C,)
    const float* ctx_b   = (const float*)d_in[8];   // (C,)
    const float* Wkv     = (const float*)d_in[9];   // (C, 2C)
    const float* Wout    = (const float*)d_in[10];  // (C, C)
    const float* bout    = (const float*)d_in[11];  // (C,)
    float* out = (float*)d_out;
    float* y   = (float*)d_ws;                      // (B, C) scratch = 8 KB

    compute_y_kernel<<<BB, CC, 0, stream>>>(param, Wparam, bparam, ctx_g, ctx_b,
                                            Wkv, Wout, bout, y);

    const int total4 = BB * NN * CC / 4;            // 524288
    bcast_add_kernel<<<total4 / 256, 256, 0, stream>>>(
        (const float4*)img, (const float4*)y, (float4*)out);
}

// Round 2
// 91.195 us; speedup vs baseline: 1.1543x; 1.1543x over previous
//
#include <hip/hip_runtime.h>
#include <math.h>

// Problem constants (from reference)
#define BB 8
#define NN 1024
#define CC 256
#define PARAM_DIM 16
#define EPS 1e-5f

// Dead-code collapse of the reference:
//   scores are broadcast over the softmax axis -> softmax is uniform ->
//   attention output == v (independent of q). So:
//     ctx = param_tokens @ Wparam + bparam          (B,256)
//     v   = layernorm(ctx) @ Wkv[:, C:2C]           (B,256)
//     y   = v @ Wout + bout                         (B,256)
//     out = img_tokens + y[:,None,:]                (B,N,C)

// One block per batch, 1024 threads.
// Matvecs use 16-way split-K with float4 weight loads (16 independent
// 16B loads in flight -> ~2 latency round-trips instead of 32).
__global__ __launch_bounds__(1024) void compute_y_kernel(
    const float* __restrict__ param,    // (B, 16)
    const float* __restrict__ Wparam,   // (16, C)
    const float* __restrict__ bparam,   // (C,)
    const float* __restrict__ ctx_g,    // (C,)
    const float* __restrict__ ctx_b,    // (C,)
    const float* __restrict__ Wkv,      // (C, 2C)
    const float* __restrict__ Wout,     // (C, C)
    const float* __restrict__ bout,     // (C,)
    float* __restrict__ y)              // (B, C) out
{
    const int b  = blockIdx.x;
    const int t  = threadIdx.x;         // 0..1023
    const int c  = t & 255;             // output channel (4x replicated)
    const int c4 = t & 63;              // float4 column group
    const int k  = t >> 6;              // split-K index 0..15

    __shared__ float  sln[CC];          // layernormed ctx
    __shared__ float  sv[CC];           // v
    __shared__ float4 smp[1024];        // split-K partials (16 KB)
    __shared__ float  red[16];          // wave partial sums
    __shared__ float  p[PARAM_DIM];

    if (t < PARAM_DIM) p[t] = param[b * PARAM_DIM + t];
    __syncthreads();

    // ---- ctx[c] = bparam[c] + sum_j p[j] * Wparam[j][c]  (replicated 4x) ----
    float ctx = bparam[c];
    #pragma unroll
    for (int j = 0; j < PARAM_DIM; ++j)
        ctx = fmaf(p[j], Wparam[j * CC + c], ctx);

    // ---- layernorm: block reduction over 1024 threads (each value 4x) ----
    float s = ctx;
    #pragma unroll
    for (int o = 32; o > 0; o >>= 1) s += __shfl_down(s, o, 64);
    if ((t & 63) == 0) red[t >> 6] = s;
    __syncthreads();
    float tot = 0.0f;
    #pragma unroll
    for (int i = 0; i < 16; ++i) tot += red[i];
    const float mean = tot * (1.0f / 1024.0f);

    const float d = ctx - mean;
    float s2 = d * d;
    __syncthreads();                    // red[] reuse
    #pragma unroll
    for (int o = 32; o > 0; o >>= 1) s2 += __shfl_down(s2, o, 64);
    if ((t & 63) == 0) red[t >> 6] = s2;
    __syncthreads();
    tot = 0.0f;
    #pragma unroll
    for (int i = 0; i < 16; ++i) tot += red[i];
    const float var = tot * (1.0f / 1024.0f);

    const float ln = d * rsqrtf(var + EPS) * ctx_g[c] + ctx_b[c];
    if (t < CC) sln[c] = ln;
    __syncthreads();

    // ---- v = ln @ Wkv[:, C:2C]  (split-K=16, float4 columns) ----
    // Wkv row j = 128 float4; V half starts at float4 index 64.
    const float4* __restrict__ Wkv4 = (const float4*)Wkv;
    float4 acc = make_float4(0.f, 0.f, 0.f, 0.f);
    #pragma unroll
    for (int jj = 0; jj < 16; ++jj) {
        const int j = k * 16 + jj;
        const float a = sln[j];
        const float4 w = Wkv4[j * 128 + 64 + c4];
        acc.x = fmaf(a, w.x, acc.x);
        acc.y = fmaf(a, w.y, acc.y);
        acc.z = fmaf(a, w.z, acc.z);
        acc.w = fmaf(a, w.w, acc.w);
    }
    smp[t] = acc;                       // index = k*64 + c4
    __syncthreads();
    if (t < 64) {                       // reduce 16 partials per column group
        float4 r = smp[c4];
        #pragma unroll
        for (int kk = 1; kk < 16; ++kk) {
            const float4 q = smp[kk * 64 + c4];
            r.x += q.x; r.y += q.y; r.z += q.z; r.w += q.w;
        }
        sv[c4 * 4 + 0] = r.x; sv[c4 * 4 + 1] = r.y;
        sv[c4 * 4 + 2] = r.z; sv[c4 * 4 + 3] = r.w;
    }
    __syncthreads();

    // ---- y = v @ Wout + bout  (split-K=16, float4 columns) ----
    const float4* __restrict__ Wout4 = (const float4*)Wout;  // row j = 64 float4
    acc = make_float4(0.f, 0.f, 0.f, 0.f);
    #pragma unroll
    for (int jj = 0; jj < 16; ++jj) {
        const int j = k * 16 + jj;
        const float a = sv[j];
        const float4 w = Wout4[j * 64 + c4];
        acc.x = fmaf(a, w.x, acc.x);
        acc.y = fmaf(a, w.y, acc.y);
        acc.z = fmaf(a, w.z, acc.z);
        acc.w = fmaf(a, w.w, acc.w);
    }
    smp[t] = acc;
    __syncthreads();
    if (t < 64) {
        float4 r = smp[c4];
        #pragma unroll
        for (int kk = 1; kk < 16; ++kk) {
            const float4 q = smp[kk * 64 + c4];
            r.x += q.x; r.y += q.y; r.z += q.z; r.w += q.w;
        }
        const float4 bo = ((const float4*)bout)[c4];
        r.x += bo.x; r.y += bo.y; r.z += bo.z; r.w += bo.w;
        ((float4*)y)[b * 64 + c4] = r;
    }
}

// out[b,n,:] = img[b,n,:] + y[b,:]  — float4 vectorized, HBM-roofline.
__global__ __launch_bounds__(256) void bcast_add_kernel(
    const float4* __restrict__ img4,
    const float4* __restrict__ y4,      // (B, 64) float4 rows
    float4* __restrict__ out4)
{
    const int i4 = blockIdx.x * blockDim.x + threadIdx.x;   // < 524288
    const int b  = i4 >> 16;            // N*C/4 = 65536 float4 per batch
    const int c4 = i4 & 63;             // C/4 = 64 float4 per row
    float4 a = img4[i4];
    const float4 yy = y4[b * 64 + c4];
    a.x += yy.x; a.y += yy.y; a.z += yy.z; a.w += yy.w;
    out4[i4] = a;
}

extern "C" void kernel_launch(void* const* d_in, const int* in_sizes, int n_in,
                              void* d_out, int out_size, void* d_ws, size_t ws_size,
                              hipStream_t stream) {
    const float* img     = (const float*)d_in[0];   // (B, N, C)
    const float* param   = (const float*)d_in[1];   // (B, 16)
    // d_in[2] img_norm_g, d_in[3] img_norm_b, d_in[4] Wq -> dead code
    const float* Wparam  = (const float*)d_in[5];   // (16, C)
    const float* bparam  = (const float*)d_in[6];   // (C,)
    const float* ctx_g   = (const float*)d_in[7];   // (C,)
    const float* ctx_b   = (const float*)d_in[8];   // (C,)
    const float* Wkv     = (const float*)d_in[9];   // (C, 2C)
    const float* Wout    = (const float*)d_in[10];  // (C, C)
    const float* bout    = (const float*)d_in[11];  // (C,)
    float* out = (float*)d_out;
    float* y   = (float*)d_ws;                      // (B, C) scratch = 8 KB

    compute_y_kernel<<<BB, 1024, 0, stream>>>(param, Wparam, bparam, ctx_g, ctx_b,
                                              Wkv, Wout, bout, y);

    const int total4 = BB * NN * CC / 4;            // 524288
    bcast_add_kernel<<<total4 / 256, 256, 0, stream>>>(
        (const float4*)img, (const float4*)y, (float4*)out);
}